// Round 18
// baseline (43.036 us; speedup 1.0000x reference)
//
#include <hip/hip_runtime.h>

// input x: (B=256,T=600,J=25,C=3) f32; x[b,tt,n*5+p,c] = in[(b*600+tt)*75 + n*15 + p*3 + c]
// output: (B,5,1800,4,4) f32, 3 window groups g: tout = g*600+tt.
//
// R18 = R17 (37.5us: CH=100, 512-thr, dedup single compute batch, obuf transpose,
// nt lane-contiguous stores, lgkm-only barriers) + precomputed store addressing
// (decoded into registers BEFORE the stage barrier, store loop = ds_read+store only)
// + nontemporal input loads (read-once stream, no L2 value).

#define T_ 600
#define CH_ 100
#define NCH_ 6

typedef float fx4 __attribute__((ext_vector_type(4)));

// LDS-only barrier: order LDS ops but let global stores stay in flight.
#define BAR_LDS() do { asm volatile("s_waitcnt lgkmcnt(0)" ::: "memory"); \
                       __builtin_amdgcn_s_barrier(); } while (0)

__global__ __launch_bounds__(512) void gauss_agg_kernel(const float* __restrict__ x,
                                                        float* __restrict__ out) {
    // raw: [0,7500) rows tc..tc+99; [7500,7575) row tc-1; [7575,7650) row tc+100
    __shared__ float raw[7650];        // 30.6 KB
    __shared__ float4 obuf[512 * 5];   // 40 KB; 80B/slot stride avoids bank degeneracy

    int blk = blockIdx.x;
    int ch  = blk % NCH_;
    int b   = blk / NCH_;
    int tc  = ch * CH_;
    int tid = (int)threadIdx.x;

    // window-boundary tts inside this chunk (up to two)
    int vtt1 = -1, vtt2 = -1;
    switch (ch) {
        case 0: vtt1 = 0;   break;
        case 1: vtt1 = 199; break;
        case 2: vtt1 = 200; vtt2 = 299; break;
        case 3: vtt1 = 300; vtt2 = 399; break;
        case 4: vtt1 = 400; break;
        case 5: vtt1 = 599; break;
    }

    // ---- stage (nontemporal): main 100 rows vectorized, halo scalar ----
    {
        const fx4* srcv = reinterpret_cast<const fx4*>(x + ((size_t)b * T_ + tc) * 75);
        fx4* rawv = reinterpret_cast<fx4*>(raw);
        #pragma unroll
        for (int i = 0; i < 4; ++i) {
            int e = i * 512 + tid;
            if (e < 1875) rawv[e] = __builtin_nontemporal_load(&srcv[e]);
        }
        if (tid < 150) {
            int rp  = (tid < 75) ? (tc > 0 ? tc - 1 : 0)
                                 : (tc + CH_ < T_ ? tc + CH_ : T_ - 1);
            int col = (tid < 75) ? tid : tid - 75;
            raw[7500 + tid] = __builtin_nontemporal_load(&x[((size_t)b * T_ + rp) * 75 + col]);
        }
    }

    // ---- precompute store addressing (no LDS dependency; overlaps stage latency) ----
    int   oidx[12];      // obuf float4 index per store iteration (statically indexed)
    unsigned oofs[12];   // output float4 index (fits u32: max 36.9M)
    #pragma unroll
    for (int k = 0; k < 12; ++k) {
        int f = k * 512 + tid;
        int sl = f >> 2, pc = f & 3;
        if (sl > 1499) sl = 1499;      // clamp dead lanes (guarded at store)
        int n  = sl / 300;
        int q  = sl - n * 300;
        int w  = q / 100;
        int tl = q - w * 100;
        int tt = tc + tl;
        bool bd;
        if (w == 0)      bd = (tt == 0) || (tt == 599);
        else if (w == 1) { int r = tt % 300; bd = (r == 0) || (r == 299); }
        else             { int r = tt % 200; bd = (r == 0) || (r == 199); }
        int oi;
        if (!bd)             oi = n * 100 + tl;
        else if (tt == vtt1) oi = 500 + n;
        else                 oi = 505 + n;
        oidx[k] = oi * 5 + pc;
        oofs[k] = (unsigned)(((b * 5 + n) * 1800 + w * 600 + tt) * 4 + pc);
    }
    BAR_LDS();

    const float w5[5] = {4.f, 2.f, 3.f, 2.f, 4.f};
    fx4* outf4 = reinterpret_cast<fx4*>(out);

    // ---- compute: ONE batch of 510 unique slots ----
    if (tid < 510) {
        bool isvar = (tid >= 500);
        int n, tt;
        if (!isvar) { n = tid / 100; tt = tc + (tid - n * 100); }
        else if (tid < 505) { n = tid - 500; tt = (vtt1 < 0) ? tc : vtt1; }
        else                { n = tid - 505; tt = (vtt2 < 0) ? tc : vtt2; }
        int tl = tt - tc;

        int midoff = tl * 75 + n * 15;
        const float* rc = &raw[midoff];
        const float* r0 = &raw[(tl == 0)  ? 7500 + n * 15 : midoff - 75];
        const float* r1 = &raw[(tl == 99) ? 7575 + n * 15 : midoff + 75];

        float s0=0.f,s1=0.f,s2=0.f, m0=0.f,m1=0.f,m2=0.f;
        float A00=0.f,A01=0.f,A02=0.f,A11=0.f,A12=0.f,A22=0.f;
        #pragma unroll
        for (int p = 0; p < 5; ++p) {
            float a = rc[p*3+0], c = rc[p*3+1], d = rc[p*3+2];
            s0 += a; s1 += c; s2 += d;
            m0 += w5[p]*a; m1 += w5[p]*c; m2 += w5[p]*d;
            A00 += a*a; A01 += a*c; A02 += a*d;
            A11 += c*c; A12 += c*d; A22 += d*d;
        }
        float mu0 = m0*(1.f/15.f), mu1 = m1*(1.f/15.f), mu2 = m2*(1.f/15.f);

        float inv = 0.2f;
        if (!isvar) {
            #pragma unroll
            for (int dstep = 0; dstep < 2; ++dstep) {
                const float* rn = dstep ? r1 : r0;
                #pragma unroll
                for (int p = 0; p < 5; ++p) {
                    float a = rn[p*3+0], c = rn[p*3+1], d = rn[p*3+2];
                    s0 += a; s1 += c; s2 += d;
                    A00 += a*a; A01 += a*c; A02 += a*d;
                    A11 += c*c; A12 += c*d; A22 += d*d;
                }
            }
            inv = 1.f/15.f;
        }

        float mb0 = s0*inv, mb1 = s1*inv, mb2 = s2*inv;
        float e00 = A00*inv - 2.f*mu0*mb0 + 2.f*mu0*mu0;
        float e01 = A01*inv - mu0*mb1 - mb0*mu1 + 2.f*mu0*mu1;
        float e02 = A02*inv - mu0*mb2 - mb0*mu2 + 2.f*mu0*mu2;
        float e11 = A11*inv - 2.f*mu1*mb1 + 2.f*mu1*mu1;
        float e12 = A12*inv - mu1*mb2 - mb1*mu2 + 2.f*mu1*mu2;
        float e22 = A22*inv - 2.f*mu2*mb2 + 2.f*mu2*mu2;

        int base = tid * 5;
        obuf[base + 0] = make_float4(e00, e01, e02, mu0);
        obuf[base + 1] = make_float4(e01, e11, e12, mu1);
        obuf[base + 2] = make_float4(e02, e12, e22, mu2);
        obuf[base + 3] = make_float4(mu0, mu1, mu2, 1.f);
    }
    BAR_LDS();

    // ---- store: pure ds_read + nontemporal store (addresses preloaded) ----
    #pragma unroll
    for (int k = 0; k < 12; ++k) {
        if (k * 512 + tid < 6000) {
            float4 v = obuf[oidx[k]];
            fx4 nv; nv.x = v.x; nv.y = v.y; nv.z = v.z; nv.w = v.w;
            __builtin_nontemporal_store(nv, &outf4[oofs[k]]);
        }
    }
}

extern "C" void kernel_launch(void* const* d_in, const int* in_sizes, int n_in,
                              void* d_out, int out_size, void* d_ws, size_t ws_size,
                              hipStream_t stream) {
    const float* x = (const float*)d_in[0];
    float* out = (float*)d_out;
    gauss_agg_kernel<<<256 * NCH_, 512, 0, stream>>>(x, out);
}

// Round 19
// 37.970 us; speedup vs baseline: 1.1334x; 1.1334x over previous
//
#include <hip/hip_runtime.h>

// input x: (B=256,T=600,J=25,C=3) f32; x[b,tt,n*5+p,c] = in[(b*600+tt)*75 + n*15 + p*3 + c]
// output: (B,5,1800,4,4) f32, 3 window groups g: tout = g*600+tt.
//
// R19 = R17 (37.5us) with obuf UNIONed into raw: compute holds its 9 unique
// results in registers across an extra lgkm-barrier, then writes the 32.6KB
// stride-4 obuf over the raw region. LDS 70.6 -> 32.8KB => 4 blocks/CU (32
// waves, occupancy cap) vs 2 -- smoother per-CU stage/compute/store phase mix.
// Slot-rotated piece placement (oi*4 + ((pc+oi)&3)) avoids write-bank
// degeneracy; store-sweep reads stay linear per 4 lanes (conflict-free).

#define T_ 600
#define CH_ 100
#define NCH_ 6

typedef float fx4 __attribute__((ext_vector_type(4)));

// LDS-only barrier: order LDS ops but let global stores stay in flight.
#define BAR_LDS() do { asm volatile("s_waitcnt lgkmcnt(0)" ::: "memory"); \
                       __builtin_amdgcn_s_barrier(); } while (0)

__global__ __launch_bounds__(512) void gauss_agg_kernel(const float* __restrict__ x,
                                                        float* __restrict__ out) {
    // union region: stage uses floats [0,7650); after compute, float4[0,2040)
    // holds the deduped output blocks (stride 4/slot, rotated pieces). 32.8 KB.
    __shared__ float4 lds4[2048];
    float* raw = reinterpret_cast<float*>(lds4);

    int blk = blockIdx.x;
    int ch  = blk % NCH_;
    int b   = blk / NCH_;
    int tc  = ch * CH_;
    int tid = (int)threadIdx.x;

    // window-boundary tts inside this chunk (up to two)
    int vtt1 = -1, vtt2 = -1;
    switch (ch) {
        case 0: vtt1 = 0;   break;
        case 1: vtt1 = 199; break;
        case 2: vtt1 = 200; vtt2 = 299; break;
        case 3: vtt1 = 300; vtt2 = 399; break;
        case 4: vtt1 = 400; break;
        case 5: vtt1 = 599; break;
    }

    // ---- stage: main 100 rows vectorized (16B-aligned), halo rows scalar ----
    {
        const float4* srcv = reinterpret_cast<const float4*>(x + ((size_t)b * T_ + tc) * 75);
        float4* rawv = reinterpret_cast<float4*>(raw);
        #pragma unroll
        for (int i = 0; i < 4; ++i) {
            int e = i * 512 + tid;
            if (e < 1875) rawv[e] = srcv[e];
        }
        if (tid < 150) {
            int rp  = (tid < 75) ? (tc > 0 ? tc - 1 : 0)
                                 : (tc + CH_ < T_ ? tc + CH_ : T_ - 1);
            int col = (tid < 75) ? tid : tid - 75;
            raw[7500 + tid] = x[((size_t)b * T_ + rp) * 75 + col];
        }
    }
    BAR_LDS();

    const float w5[5] = {4.f, 2.f, 3.f, 2.f, 4.f};
    fx4* outf4 = reinterpret_cast<fx4*>(out);

    // ---- compute: ONE batch of 510 unique slots -> 9 registers ----
    bool active = (tid < 510);
    float e00=0.f,e01=0.f,e02=0.f,e11=0.f,e12=0.f,e22=0.f,mu0=0.f,mu1=0.f,mu2=0.f;
    if (active) {
        bool isvar = (tid >= 500);
        int n, tt;
        if (!isvar) { n = tid / 100; tt = tc + (tid - n * 100); }
        else if (tid < 505) { n = tid - 500; tt = (vtt1 < 0) ? tc : vtt1; }
        else                { n = tid - 505; tt = (vtt2 < 0) ? tc : vtt2; }
        int tl = tt - tc;

        int midoff = tl * 75 + n * 15;
        const float* rc = &raw[midoff];
        const float* r0 = &raw[(tl == 0)  ? 7500 + n * 15 : midoff - 75];
        const float* r1 = &raw[(tl == 99) ? 7575 + n * 15 : midoff + 75];

        float s0=0.f,s1=0.f,s2=0.f, m0=0.f,m1=0.f,m2=0.f;
        float A00=0.f,A01=0.f,A02=0.f,A11=0.f,A12=0.f,A22=0.f;
        #pragma unroll
        for (int p = 0; p < 5; ++p) {
            float a = rc[p*3+0], c = rc[p*3+1], d = rc[p*3+2];
            s0 += a; s1 += c; s2 += d;
            m0 += w5[p]*a; m1 += w5[p]*c; m2 += w5[p]*d;
            A00 += a*a; A01 += a*c; A02 += a*d;
            A11 += c*c; A12 += c*d; A22 += d*d;
        }
        mu0 = m0*(1.f/15.f); mu1 = m1*(1.f/15.f); mu2 = m2*(1.f/15.f);

        float inv = 0.2f;
        if (!isvar) {
            #pragma unroll
            for (int dstep = 0; dstep < 2; ++dstep) {
                const float* rn = dstep ? r1 : r0;
                #pragma unroll
                for (int p = 0; p < 5; ++p) {
                    float a = rn[p*3+0], c = rn[p*3+1], d = rn[p*3+2];
                    s0 += a; s1 += c; s2 += d;
                    A00 += a*a; A01 += a*c; A02 += a*d;
                    A11 += c*c; A12 += c*d; A22 += d*d;
                }
            }
            inv = 1.f/15.f;
        }

        float mb0 = s0*inv, mb1 = s1*inv, mb2 = s2*inv;
        e00 = A00*inv - 2.f*mu0*mb0 + 2.f*mu0*mu0;
        e01 = A01*inv - mu0*mb1 - mb0*mu1 + 2.f*mu0*mu1;
        e02 = A02*inv - mu0*mb2 - mb0*mu2 + 2.f*mu0*mu2;
        e11 = A11*inv - 2.f*mu1*mb1 + 2.f*mu1*mu1;
        e12 = A12*inv - mu1*mb2 - mb1*mu2 + 2.f*mu1*mu2;
        e22 = A22*inv - 2.f*mu2*mb2 + 2.f*mu2*mu2;
    }
    BAR_LDS();   // all raw reads complete before overwrite

    // ---- write deduped blocks over the raw region (rotated placement) ----
    if (active) {
        int o4 = tid * 4;
        lds4[o4 + (( 0 + tid) & 3)] = make_float4(e00, e01, e02, mu0);
        lds4[o4 + (( 1 + tid) & 3)] = make_float4(e01, e11, e12, mu1);
        lds4[o4 + (( 2 + tid) & 3)] = make_float4(e02, e12, e22, mu2);
        lds4[o4 + (( 3 + tid) & 3)] = make_float4(mu0, mu1, mu2, 1.f);
    }
    BAR_LDS();

    // ---- store: 1500 slots x 4 pieces, lane-contiguous nontemporal ----
    #pragma unroll
    for (int k = 0; k < 12; ++k) {
        int f = k * 512 + tid;
        if (f < 6000) {
            int sl = f >> 2, pc = f & 3;
            int n  = sl / 300;
            int q  = sl - n * 300;
            int w  = q / 100;
            int tl = q - w * 100;
            int tt = tc + tl;
            bool bd;
            if (w == 0)      bd = (tt == 0) || (tt == 599);
            else if (w == 1) { int r = tt % 300; bd = (r == 0) || (r == 299); }
            else             { int r = tt % 200; bd = (r == 0) || (r == 199); }
            int oi;
            if (!bd)             oi = n * 100 + tl;
            else if (tt == vtt1) oi = 500 + n;
            else                 oi = 505 + n;
            size_t o = ((size_t)(b * 5 + n) * 1800 + w * 600 + tt) * 4 + pc;
            float4 v = lds4[oi * 4 + ((pc + oi) & 3)];
            fx4 nv; nv.x = v.x; nv.y = v.y; nv.z = v.z; nv.w = v.w;
            __builtin_nontemporal_store(nv, &outf4[o]);
        }
    }
}

extern "C" void kernel_launch(void* const* d_in, const int* in_sizes, int n_in,
                              void* d_out, int out_size, void* d_ws, size_t ws_size,
                              hipStream_t stream) {
    const float* x = (const float*)d_in[0];
    float* out = (float*)d_out;
    gauss_agg_kernel<<<256 * NCH_, 512, 0, stream>>>(x, out);
}

// Round 20
// 36.699 us; speedup vs baseline: 1.1727x; 1.0346x over previous
//
#include <hip/hip_runtime.h>

// input x: (B=256,T=600,J=25,C=3) f32; x[b,tt,n*5+p,c] = in[(b*600+tt)*75 + n*15 + p*3 + c]
// output: (B,5,1800,4,4) f32, 3 window groups g: tout = g*600+tt.
//
// R20 = R17 (37.5us: CH=100, 512-thr, dedup single compute batch, bank-padded obuf,
// nt lane-contiguous stores, lgkm-only barriers) + global_load_lds DMA staging:
// main 1875 float4 staged by 4 exec-uniform DMA instrs/wave (width 16, no VGPR
// round-trip). Tail lanes clamp the GLOBAL index (dup loads, dest in dead pad
// [7500,8192)); halo rows moved to raw[8192..8342) so DMA and ds_write regions
// are disjoint (no ordering hazard). Stage barrier = __syncthreads (vmcnt drain
// needed for DMA; free at block start). x total = 2,880,000 float4s.

#define T_ 600
#define CH_ 100
#define NCH_ 6

typedef float fx4 __attribute__((ext_vector_type(4)));
typedef const __attribute__((address_space(1))) void* gas_t;
typedef __attribute__((address_space(3))) void* las_t;

// LDS-only barrier: order LDS ops but let global stores stay in flight.
#define BAR_LDS() do { asm volatile("s_waitcnt lgkmcnt(0)" ::: "memory"); \
                       __builtin_amdgcn_s_barrier(); } while (0)

__global__ __launch_bounds__(512) void gauss_agg_kernel(const float* __restrict__ x,
                                                        float* __restrict__ out) {
    // raw: [0,7500) main rows tc..tc+99 (DMA); [7500,8192) dead pad (DMA tail dups);
    // [8192,8267) row tc-1; [8267,8342) row tc+100. 33.4 KB.
    __shared__ float raw[8344];
    __shared__ float4 obuf[512 * 5];   // 40 KB; 80B/slot stride avoids bank degeneracy

    int blk = blockIdx.x;
    int ch  = blk % NCH_;
    int b   = blk / NCH_;
    int tc  = ch * CH_;
    int tid = (int)threadIdx.x;
    int wv  = tid >> 6;

    // window-boundary tts inside this chunk (up to two)
    int vtt1 = -1, vtt2 = -1;
    switch (ch) {
        case 0: vtt1 = 0;   break;
        case 1: vtt1 = 199; break;
        case 2: vtt1 = 200; vtt2 = 299; break;
        case 3: vtt1 = 300; vtt2 = 399; break;
        case 4: vtt1 = 400; break;
        case 5: vtt1 = 599; break;
    }

    // ---- stage: DMA main region (4 wave-uniform-dest instrs), scalar halo ----
    {
        size_t base4 = ((size_t)((b * 600 + tc) * 75)) >> 2;   // (b*600+tc)%4==0 -> exact
        const float4* srcv = reinterpret_cast<const float4*>(x);
        float4* raw4 = reinterpret_cast<float4*>(raw);
        #pragma unroll
        for (int i = 0; i < 4; ++i) {
            size_t g4 = base4 + (size_t)(i * 512 + tid);
            if (g4 > 2879999) g4 = 2879999;            // clamp source; dest hits dead pad
            float4* ldst = raw4 + (i * 512 + wv * 64); // wave-uniform LDS base
            __builtin_amdgcn_global_load_lds((gas_t)(srcv + g4), (las_t)ldst, 16, 0, 0);
        }
        if (tid < 150) {
            int rp  = (tid < 75) ? (tc > 0 ? tc - 1 : 0)
                                 : (tc + CH_ < T_ ? tc + CH_ : T_ - 1);
            int col = (tid < 75) ? tid : tid - 75;
            raw[8192 + tid] = x[((size_t)b * T_ + rp) * 75 + col];
        }
    }
    __syncthreads();   // drains DMA (vmcnt) + halo ds_writes; no stores outstanding yet

    const float w5[5] = {4.f, 2.f, 3.f, 2.f, 4.f};
    fx4* outf4 = reinterpret_cast<fx4*>(out);

    // ---- compute: ONE batch of 510 unique slots ----
    if (tid < 510) {
        bool isvar = (tid >= 500);
        int n, tt;
        if (!isvar) { n = tid / 100; tt = tc + (tid - n * 100); }
        else if (tid < 505) { n = tid - 500; tt = (vtt1 < 0) ? tc : vtt1; }
        else                { n = tid - 505; tt = (vtt2 < 0) ? tc : vtt2; }
        int tl = tt - tc;

        int midoff = tl * 75 + n * 15;
        const float* rc = &raw[midoff];
        const float* r0 = &raw[(tl == 0)  ? 8192 + n * 15 : midoff - 75];
        const float* r1 = &raw[(tl == 99) ? 8267 + n * 15 : midoff + 75];

        float s0=0.f,s1=0.f,s2=0.f, m0=0.f,m1=0.f,m2=0.f;
        float A00=0.f,A01=0.f,A02=0.f,A11=0.f,A12=0.f,A22=0.f;
        #pragma unroll
        for (int p = 0; p < 5; ++p) {
            float a = rc[p*3+0], c = rc[p*3+1], d = rc[p*3+2];
            s0 += a; s1 += c; s2 += d;
            m0 += w5[p]*a; m1 += w5[p]*c; m2 += w5[p]*d;
            A00 += a*a; A01 += a*c; A02 += a*d;
            A11 += c*c; A12 += c*d; A22 += d*d;
        }
        float mu0 = m0*(1.f/15.f), mu1 = m1*(1.f/15.f), mu2 = m2*(1.f/15.f);

        float inv = 0.2f;
        if (!isvar) {
            #pragma unroll
            for (int dstep = 0; dstep < 2; ++dstep) {
                const float* rn = dstep ? r1 : r0;
                #pragma unroll
                for (int p = 0; p < 5; ++p) {
                    float a = rn[p*3+0], c = rn[p*3+1], d = rn[p*3+2];
                    s0 += a; s1 += c; s2 += d;
                    A00 += a*a; A01 += a*c; A02 += a*d;
                    A11 += c*c; A12 += c*d; A22 += d*d;
                }
            }
            inv = 1.f/15.f;
        }

        float mb0 = s0*inv, mb1 = s1*inv, mb2 = s2*inv;
        float e00 = A00*inv - 2.f*mu0*mb0 + 2.f*mu0*mu0;
        float e01 = A01*inv - mu0*mb1 - mb0*mu1 + 2.f*mu0*mu1;
        float e02 = A02*inv - mu0*mb2 - mb0*mu2 + 2.f*mu0*mu2;
        float e11 = A11*inv - 2.f*mu1*mb1 + 2.f*mu1*mu1;
        float e12 = A12*inv - mu1*mb2 - mb1*mu2 + 2.f*mu1*mu2;
        float e22 = A22*inv - 2.f*mu2*mb2 + 2.f*mu2*mu2;

        int base = tid * 5;
        obuf[base + 0] = make_float4(e00, e01, e02, mu0);
        obuf[base + 1] = make_float4(e01, e11, e12, mu1);
        obuf[base + 2] = make_float4(e02, e12, e22, mu2);
        obuf[base + 3] = make_float4(mu0, mu1, mu2, 1.f);
    }
    BAR_LDS();

    // ---- store: 1500 slots x 4 pieces, lane-contiguous nontemporal ----
    #pragma unroll
    for (int k = 0; k < 12; ++k) {
        int f = k * 512 + tid;
        if (f < 6000) {
            int sl = f >> 2, pc = f & 3;
            int n  = sl / 300;
            int q  = sl - n * 300;
            int w  = q / 100;
            int tl = q - w * 100;
            int tt = tc + tl;
            bool bd;
            if (w == 0)      bd = (tt == 0) || (tt == 599);
            else if (w == 1) { int r = tt % 300; bd = (r == 0) || (r == 299); }
            else             { int r = tt % 200; bd = (r == 0) || (r == 199); }
            int oi;
            if (!bd)             oi = n * 100 + tl;
            else if (tt == vtt1) oi = 500 + n;
            else                 oi = 505 + n;
            size_t o = ((size_t)(b * 5 + n) * 1800 + w * 600 + tt) * 4 + pc;
            float4 v = obuf[oi * 5 + pc];
            fx4 nv; nv.x = v.x; nv.y = v.y; nv.z = v.z; nv.w = v.w;
            __builtin_nontemporal_store(nv, &outf4[o]);
        }
    }
}

extern "C" void kernel_launch(void* const* d_in, const int* in_sizes, int n_in,
                              void* d_out, int out_size, void* d_ws, size_t ws_size,
                              hipStream_t stream) {
    const float* x = (const float*)d_in[0];
    float* out = (float*)d_out;
    gauss_agg_kernel<<<256 * NCH_, 512, 0, stream>>>(x, out);
}

// Round 21
// 35.622 us; speedup vs baseline: 1.2081x; 1.0302x over previous
//
#include <hip/hip_runtime.h>

// input x: (B=256,T=600,J=25,C=3) f32; x[b,tt,n*5+p,c] = in[(b*600+tt)*75 + n*15 + p*3 + c]
// output: (B,5,1800,4,4) f32, 3 window groups g: tout = g*600+tt.
//
// R21 = R20 (36.7us) with the stage unified into ONE linear DMA region:
// rows [s_row, e_row) = tc-1 .. tc+100 staged contiguously; start rounded down
// to 16B (off<=3 floats, compute reads raw[off + li*75 + ...]); tail DMA lanes
// clamp the GLOBAL index and land in LDS slack [1913,2048). No scalar halo
// loads, no halo tail regions, no compute-path ternaries.

#define T_ 600
#define CH_ 100
#define NCH_ 6
#define NF4_ 2880000   // total float4s in x

typedef float fx4 __attribute__((ext_vector_type(4)));
typedef const __attribute__((address_space(1))) void* gas_t;
typedef __attribute__((address_space(3))) void* las_t;

// LDS-only barrier: order LDS ops but let global stores stay in flight.
#define BAR_LDS() do { asm volatile("s_waitcnt lgkmcnt(0)" ::: "memory"); \
                       __builtin_amdgcn_s_barrier(); } while (0)

__global__ __launch_bounds__(512) void gauss_agg_kernel(const float* __restrict__ x,
                                                        float* __restrict__ out) {
    __shared__ float4 raw4[2048];      // 32.8 KB staged superset (+slack)
    __shared__ float4 obuf[512 * 5];   // 40 KB; 80B/slot stride avoids bank degeneracy
    float* raw = reinterpret_cast<float*>(raw4);

    int blk = blockIdx.x;
    int ch  = blk % NCH_;
    int b   = blk / NCH_;
    int tc  = ch * CH_;
    int tid = (int)threadIdx.x;
    int wv  = tid >> 6;

    // window-boundary tts inside this chunk (up to two)
    int vtt1 = -1, vtt2 = -1;
    switch (ch) {
        case 0: vtt1 = 0;   break;
        case 1: vtt1 = 199; break;
        case 2: vtt1 = 200; vtt2 = 299; break;
        case 3: vtt1 = 300; vtt2 = 399; break;
        case 4: vtt1 = 400; break;
        case 5: vtt1 = 599; break;
    }

    int s_row = (tc > 0) ? tc - 1 : 0;
    int e_row = tc + CH_ + 1; if (e_row > T_) e_row = T_;
    int r0  = (b * 600 + s_row) * 75;       // first needed float (global index)
    int a0  = r0 & ~3;                      // 16B-aligned DMA start
    int off = r0 - a0;                      // 0..3
    int nfl = off + (e_row - s_row) * 75;   // floats to stage
    int n4  = (nfl + 3) >> 2;               // float4s (<= 1913)

    // ---- stage: one linear DMA region, 4 wave-uniform instrs ----
    {
        const float4* srcv = reinterpret_cast<const float4*>(x);
        int base4 = a0 >> 2;
        #pragma unroll
        for (int i = 0; i < 4; ++i) {
            int e  = i * 512 + tid;
            int g4 = base4 + ((e < n4) ? e : (n4 - 1));   // clamp source for tail lanes
            float4* ldst = raw4 + (i * 512 + wv * 64);    // wave-uniform LDS base
            __builtin_amdgcn_global_load_lds((gas_t)(srcv + g4), (las_t)ldst, 16, 0, 0);
        }
    }
    __syncthreads();   // drains DMA (vmcnt); no stores outstanding at block start

    const float w5[5] = {4.f, 2.f, 3.f, 2.f, 4.f};
    fx4* outf4 = reinterpret_cast<fx4*>(out);

    // ---- compute: ONE batch of 510 unique slots ----
    if (tid < 510) {
        bool isvar = (tid >= 500);
        int n, tt;
        if (!isvar) { n = tid / 100; tt = tc + (tid - n * 100); }
        else if (tid < 505) { n = tid - 500; tt = (vtt1 < 0) ? tc : vtt1; }
        else                { n = tid - 505; tt = (vtt2 < 0) ? tc : vtt2; }

        int li = tt - s_row;
        int midoff = off + li * 75 + n * 15;
        const float* rc = &raw[midoff];
        const float* r0p = rc - 75;    // valid for all interior slots (s_row <= tt-1)
        const float* r1p = rc + 75;    // valid for all interior slots (e_row >= tt+2)

        float s0=0.f,s1=0.f,s2=0.f, m0=0.f,m1=0.f,m2=0.f;
        float A00=0.f,A01=0.f,A02=0.f,A11=0.f,A12=0.f,A22=0.f;
        #pragma unroll
        for (int p = 0; p < 5; ++p) {
            float a = rc[p*3+0], c = rc[p*3+1], d = rc[p*3+2];
            s0 += a; s1 += c; s2 += d;
            m0 += w5[p]*a; m1 += w5[p]*c; m2 += w5[p]*d;
            A00 += a*a; A01 += a*c; A02 += a*d;
            A11 += c*c; A12 += c*d; A22 += d*d;
        }
        float mu0 = m0*(1.f/15.f), mu1 = m1*(1.f/15.f), mu2 = m2*(1.f/15.f);

        float inv = 0.2f;
        if (!isvar) {
            #pragma unroll
            for (int dstep = 0; dstep < 2; ++dstep) {
                const float* rn = dstep ? r1p : r0p;
                #pragma unroll
                for (int p = 0; p < 5; ++p) {
                    float a = rn[p*3+0], c = rn[p*3+1], d = rn[p*3+2];
                    s0 += a; s1 += c; s2 += d;
                    A00 += a*a; A01 += a*c; A02 += a*d;
                    A11 += c*c; A12 += c*d; A22 += d*d;
                }
            }
            inv = 1.f/15.f;
        }

        float mb0 = s0*inv, mb1 = s1*inv, mb2 = s2*inv;
        float e00 = A00*inv - 2.f*mu0*mb0 + 2.f*mu0*mu0;
        float e01 = A01*inv - mu0*mb1 - mb0*mu1 + 2.f*mu0*mu1;
        float e02 = A02*inv - mu0*mb2 - mb0*mu2 + 2.f*mu0*mu2;
        float e11 = A11*inv - 2.f*mu1*mb1 + 2.f*mu1*mu1;
        float e12 = A12*inv - mu1*mb2 - mb1*mu2 + 2.f*mu1*mu2;
        float e22 = A22*inv - 2.f*mu2*mb2 + 2.f*mu2*mu2;

        int base = tid * 5;
        obuf[base + 0] = make_float4(e00, e01, e02, mu0);
        obuf[base + 1] = make_float4(e01, e11, e12, mu1);
        obuf[base + 2] = make_float4(e02, e12, e22, mu2);
        obuf[base + 3] = make_float4(mu0, mu1, mu2, 1.f);
    }
    BAR_LDS();

    // ---- store: 1500 slots x 4 pieces, lane-contiguous nontemporal ----
    #pragma unroll
    for (int k = 0; k < 12; ++k) {
        int f = k * 512 + tid;
        if (f < 6000) {
            int sl = f >> 2, pc = f & 3;
            int n  = sl / 300;
            int q  = sl - n * 300;
            int w  = q / 100;
            int tl = q - w * 100;
            int tt = tc + tl;
            bool bd;
            if (w == 0)      bd = (tt == 0) || (tt == 599);
            else if (w == 1) { int r = tt % 300; bd = (r == 0) || (r == 299); }
            else             { int r = tt % 200; bd = (r == 0) || (r == 199); }
            int oi;
            if (!bd)             oi = n * 100 + tl;
            else if (tt == vtt1) oi = 500 + n;
            else                 oi = 505 + n;
            size_t o = ((size_t)(b * 5 + n) * 1800 + w * 600 + tt) * 4 + pc;
            float4 v = obuf[oi * 5 + pc];
            fx4 nv; nv.x = v.x; nv.y = v.y; nv.z = v.z; nv.w = v.w;
            __builtin_nontemporal_store(nv, &outf4[o]);
        }
    }
}

extern "C" void kernel_launch(void* const* d_in, const int* in_sizes, int n_in,
                              void* d_out, int out_size, void* d_ws, size_t ws_size,
                              hipStream_t stream) {
    const float* x = (const float*)d_in[0];
    float* out = (float*)d_out;
    gauss_agg_kernel<<<256 * NCH_, 512, 0, stream>>>(x, out);
}